// Round 6
// baseline (83.936 us; speedup 1.0000x reference)
//
#include <hip/hip_runtime.h>

#define NODES  28
#define PPN    320              // points per node
#define MID    13               // (NODES-2)/2
#define NPTS   (NODES * PPN)    // 8960
#define TOTPTS (2 * NPTS)       // 17920
#define SIGMA  10.0f
#define FLT_BIG 3.4e38f

#define BT    128               // threads per pair block (2 waves)
#define RPT   10                // source points per thread
#define GPTS  (BT * RPT)        // 1280 source points per block
#define NGRP  (NPTS / GPTS)     // 7 source groups per direction
#define DBT   80                // db-tile points per block
#define NDBT  (PPN / DBT)       // 4 db tiles per node

// ---------------------------------------------------------------------------
// Phase 1: one block per (direction p, src-group g, db-node b, db-tile s).
// Stage+clip+pack the 80-point db tile into LDS as (-2x,-2y,-2z,|x|^2);
// each thread owns 10 clipped source points in regs, so one broadcast
// ds_read_b128 feeds 10*64 distances (LDS pipe ~5x below the VALU floor).
// Publish via PLAIN stores into interleaved m[b][q][s] (s fastest) — no
// atomics (R5's cross-XCD atomicMin penalty), no init memset, and combine
// can fold the 4 partials with one coalesced float4 load per node.
// ---------------------------------------------------------------------------
__global__ __launch_bounds__(BT, 3)
void pair_min_kernel(const float* __restrict__ X, const float* __restrict__ T,
                     float* __restrict__ m)   // [NODES][TOTPTS][NDBT]
{
    __shared__ float4 st[DBT];

    const int bid = blockIdx.x;                       // 0 .. 1567
    const int p   = bid / (NGRP * NODES * NDBT);      // direction
    const int r1  = bid % (NGRP * NODES * NDBT);
    const int g   = r1 / (NODES * NDBT);              // source group (1280 pts)
    const int r2  = r1 % (NODES * NDBT);
    const int b   = r2 / NDBT;                        // db node
    const int s   = r2 % NDBT;                        // db tile within node

    const float* __restrict__ src = p ? T : X;
    const float* __restrict__ db  = p ? X : T;

    const int t = threadIdx.x;

    // stage + clip + pack db tile (80 pts)
    if (t < DBT) {
        const float* q = db + (size_t)(b * PPN + s * DBT + t) * 3;
        float v0 = fminf(fmaxf(q[0], -SIGMA), SIGMA);
        float v1 = fminf(fmaxf(q[1], -SIGMA), SIGMA);
        float v2 = fminf(fmaxf(q[2], -SIGMA), SIGMA);
        float n  = v0*v0 + v1*v1 + v2*v2;
        st[t] = make_float4(-2.f*v0, -2.f*v1, -2.f*v2, n);
    }

    // own source points (clip + norm), 10 per thread
    float4 sp[RPT];
    #pragma unroll
    for (int k = 0; k < RPT; ++k) {
        const float* q = src + (size_t)(g * GPTS + k * BT + t) * 3;
        float a0 = fminf(fmaxf(q[0], -SIGMA), SIGMA);
        float a1 = fminf(fmaxf(q[1], -SIGMA), SIGMA);
        float a2 = fminf(fmaxf(q[2], -SIGMA), SIGMA);
        sp[k] = make_float4(a0, a1, a2, a0*a0 + a1*a1 + a2*a2);
    }
    __syncthreads();

    float mn[RPT];
    #pragma unroll
    for (int k = 0; k < RPT; ++k) mn[k] = FLT_BIG;

    #pragma unroll 2
    for (int j = 0; j < DBT; j += 2) {
        const float4 ta = st[j];
        const float4 tb = st[j + 1];
        #pragma unroll
        for (int k = 0; k < RPT; ++k) {
            float da  = fmaf(ta.x, sp[k].x, fmaf(ta.y, sp[k].y, fmaf(ta.z, sp[k].z, ta.w)));
            float dbv = fmaf(tb.x, sp[k].x, fmaf(tb.y, sp[k].y, fmaf(tb.z, sp[k].z, tb.w)));
            mn[k] = fminf(mn[k], fminf(da, dbv));   // -> v_min3_f32
        }
    }

    // interleaved partial store: m[b][q][s], q = p*NPTS + g*GPTS + k*BT + t
    float* row = m + ((size_t)b * TOTPTS + (size_t)p * NPTS + (size_t)g * GPTS) * NDBT + s;
    #pragma unroll
    for (int k = 0; k < RPT; ++k)
        row[(size_t)(k * BT + t) * NDBT] = mn[k] + sp[k].w;
}

__inline__ __device__ float wave_reduce_sum(float v) {
    #pragma unroll
    for (int off = 32; off > 0; off >>= 1)
        v += __shfl_down(v, off, 64);
    return v;
}

// ---------------------------------------------------------------------------
// Phase 2: per point, one float4 load per node folds the 4 db-tile partials
// (coalesced: lane q reads m4[c*TOTPTS+q], 1024 B/wave). Then the 26-subset
// closed form + half-arch term; block-reduce to scalar.
// ---------------------------------------------------------------------------
__global__ __launch_bounds__(256)
void combine_kernel(const float4* __restrict__ m4,  // [NODES][TOTPTS]
                    float* __restrict__ out)
{
    const int q = blockIdx.x * blockDim.x + threadIdx.x;  // 0 .. TOTPTS-1
    float tot = 0.0f;
    if (q < TOTPTS) {
        const int a = (q % NPTS) / PPN;   // node of this point

        float r[NODES];
        #pragma unroll
        for (int c = 0; c < NODES; ++c) {
            const float4 v4 = m4[(size_t)c * TOTPTS + q];
            r[c] = fminf(fminf(v4.x, v4.y), fminf(v4.z, v4.w));
        }

        // min1 / argmin
        float min1 = FLT_BIG; int c1 = -1;
        #pragma unroll
        for (int c = 0; c < NODES; ++c) {
            if (r[c] < min1) { min1 = r[c]; c1 = c; }
        }
        // min over c != c1
        float min2 = FLT_BIG;
        #pragma unroll
        for (int c = 0; c < NODES; ++c) {
            float v = (c == c1) ? FLT_BIG : r[c];
            min2 = fminf(min2, v);
        }
        // half-arch min
        float H = FLT_BIG;
        if (a < MID) {
            #pragma unroll
            for (int c = 0; c < MID; ++c) H = fminf(H, r[c]);
        } else {
            #pragma unroll
            for (int c = MID; c < NODES; ++c) H = fminf(H, r[c]);
        }

        const int n = (a < NODES - 2) ? (NODES - 3) : (NODES - 2); // 25 or 26
        float S = (float)n * min1;
        if (c1 <= NODES - 3 && c1 != a) S -= (min1 - min2);
        if (a < NODES - 2) {
            const int dup = (a < MID) ? (a + MID) : (a - MID);
            S += (c1 == dup) ? min2 : min1;
        }
        tot = S + H;
    }

    __shared__ float warp_sums[4];
    float ws = wave_reduce_sum(tot);
    const int lane = threadIdx.x & 63;
    const int wid  = threadIdx.x >> 6;
    if (lane == 0) warp_sums[wid] = ws;
    __syncthreads();
    if (wid == 0) {
        float v = (lane < 4) ? warp_sums[lane] : 0.0f;
        v = wave_reduce_sum(v);
        if (lane == 0) atomicAdd(out, v);
    }
}

extern "C" void kernel_launch(void* const* d_in, const int* in_sizes, int n_in,
                              void* d_out, int out_size, void* d_ws, size_t ws_size,
                              hipStream_t stream) {
    const float* X = (const float*)d_in[0];
    const float* T = (const float*)d_in[1];
    float* out = (float*)d_out;
    float* m   = (float*)d_ws;               // [NODES][TOTPTS][NDBT] = 8.0 MB

    hipMemsetAsync(out, 0, sizeof(float), stream);
    pair_min_kernel<<<2 * NGRP * NODES * NDBT, BT, 0, stream>>>(X, T, m);
    combine_kernel<<<TOTPTS / 256, 256, 0, stream>>>((const float4*)m, out);
}

// Round 7
// 78.779 us; speedup vs baseline: 1.0655x; 1.0655x over previous
//
#include <hip/hip_runtime.h>

#define NODES  28
#define PPN    320              // points per node
#define MID    13               // (NODES-2)/2
#define NPTS   (NODES * PPN)    // 8960
#define TOTPTS (2 * NPTS)       // 17920
#define SIGMA  10.0f
#define FLT_BIG 3.4e38f

#define BT    128               // threads per pair block (2 waves)
#define RPT   5                 // source points per thread
#define GPTS  (BT * RPT)        // 640 source points per block
#define NGRP  (NPTS / GPTS)     // 14 source groups per direction

// ---------------------------------------------------------------------------
// Phase 1 (R3 structure, R=5): one block per (direction p, src-group g,
// db-node b). Full 320-point db node clipped+packed into LDS as
// (-2x,-2y,-2z,|x|^2); each thread owns 5 clipped source points in regs, so
// one broadcast ds_read_b128 feeds 5*64 distances (LDS pipe 24.4 -> 9.8 us).
// Publish path IDENTICAL to measured-best R3: plain coalesced stores into
// m[b][q] (2 MB, no partials, no atomics).
// ---------------------------------------------------------------------------
__global__ __launch_bounds__(BT, 2)
void pair_min_kernel(const float* __restrict__ X, const float* __restrict__ T,
                     float* __restrict__ m)   // [NODES][TOTPTS]
{
    __shared__ float4 st[PPN];

    const int bid = blockIdx.x;              // 0 .. 783
    const int p   = bid / (NGRP * NODES);    // 0: X queries vs T db; 1: T vs X
    const int r   = bid % (NGRP * NODES);
    const int g   = r / NODES;               // source group (640 pts)
    const int b   = r % NODES;               // db node

    const float* __restrict__ src = p ? T : X;
    const float* __restrict__ db  = p ? X : T;

    const int t = threadIdx.x;

    // stage + clip + pack full db node (320 pts)
    for (int j = t; j < PPN; j += BT) {
        const float* q = db + (size_t)(b * PPN + j) * 3;
        float v0 = fminf(fmaxf(q[0], -SIGMA), SIGMA);
        float v1 = fminf(fmaxf(q[1], -SIGMA), SIGMA);
        float v2 = fminf(fmaxf(q[2], -SIGMA), SIGMA);
        float n  = v0*v0 + v1*v1 + v2*v2;
        st[j] = make_float4(-2.f*v0, -2.f*v1, -2.f*v2, n);
    }

    // own source points (clip + norm), 5 per thread
    float4 sp[RPT];
    #pragma unroll
    for (int k = 0; k < RPT; ++k) {
        const float* q = src + (size_t)(g * GPTS + k * BT + t) * 3;
        float a0 = fminf(fmaxf(q[0], -SIGMA), SIGMA);
        float a1 = fminf(fmaxf(q[1], -SIGMA), SIGMA);
        float a2 = fminf(fmaxf(q[2], -SIGMA), SIGMA);
        sp[k] = make_float4(a0, a1, a2, a0*a0 + a1*a1 + a2*a2);
    }
    __syncthreads();

    float mn[RPT];
    #pragma unroll
    for (int k = 0; k < RPT; ++k) mn[k] = FLT_BIG;

    #pragma unroll 2
    for (int j = 0; j < PPN; j += 2) {
        const float4 ta = st[j];
        const float4 tb = st[j + 1];
        #pragma unroll
        for (int k = 0; k < RPT; ++k) {
            float da  = fmaf(ta.x, sp[k].x, fmaf(ta.y, sp[k].y, fmaf(ta.z, sp[k].z, ta.w)));
            float dbv = fmaf(tb.x, sp[k].x, fmaf(tb.y, sp[k].y, fmaf(tb.z, sp[k].z, tb.w)));
            mn[k] = fminf(mn[k], fminf(da, dbv));   // -> v_min3_f32
        }
    }

    // coalesced publish, identical layout to R3: m[b][q]
    float* row = m + (size_t)b * TOTPTS + ((size_t)p * NPTS + (size_t)g * GPTS);
    #pragma unroll
    for (int k = 0; k < RPT; ++k)
        row[k * BT + t] = mn[k] + sp[k].w;
}

__inline__ __device__ float wave_reduce_sum(float v) {
    #pragma unroll
    for (int off = 32; off > 0; off >>= 1)
        v += __shfl_down(v, off, 64);
    return v;
}

// ---------------------------------------------------------------------------
// Phase 2 (identical to measured-best R3): fold the 28 per-node minima into
// the 26-subset closed form + half-arch term; reduce to scalar. m[c][q]:
// for fixed c, lanes read consecutive q -> coalesced.
// ---------------------------------------------------------------------------
__global__ __launch_bounds__(256)
void combine_kernel(const float* __restrict__ m,   // [NODES][TOTPTS]
                    float* __restrict__ out)
{
    const int q = blockIdx.x * blockDim.x + threadIdx.x;  // 0 .. TOTPTS-1
    float tot = 0.0f;
    if (q < TOTPTS) {
        const int a = (q % NPTS) / PPN;   // node of this point

        float r[NODES];
        #pragma unroll
        for (int c = 0; c < NODES; ++c) r[c] = m[(size_t)c * TOTPTS + q];

        // min1 / argmin
        float min1 = FLT_BIG; int c1 = -1;
        #pragma unroll
        for (int c = 0; c < NODES; ++c) {
            if (r[c] < min1) { min1 = r[c]; c1 = c; }
        }
        // min over c != c1
        float min2 = FLT_BIG;
        #pragma unroll
        for (int c = 0; c < NODES; ++c) {
            float v = (c == c1) ? FLT_BIG : r[c];
            min2 = fminf(min2, v);
        }
        // half-arch min
        float H = FLT_BIG;
        if (a < MID) {
            #pragma unroll
            for (int c = 0; c < MID; ++c) H = fminf(H, r[c]);
        } else {
            #pragma unroll
            for (int c = MID; c < NODES; ++c) H = fminf(H, r[c]);
        }

        const int n = (a < NODES - 2) ? (NODES - 3) : (NODES - 2); // 25 or 26
        float S = (float)n * min1;
        if (c1 <= NODES - 3 && c1 != a) S -= (min1 - min2);
        if (a < NODES - 2) {
            const int dup = (a < MID) ? (a + MID) : (a - MID);
            S += (c1 == dup) ? min2 : min1;
        }
        tot = S + H;
    }

    __shared__ float warp_sums[4];
    float ws = wave_reduce_sum(tot);
    const int lane = threadIdx.x & 63;
    const int wid  = threadIdx.x >> 6;
    if (lane == 0) warp_sums[wid] = ws;
    __syncthreads();
    if (wid == 0) {
        float v = (lane < 4) ? warp_sums[lane] : 0.0f;
        v = wave_reduce_sum(v);
        if (lane == 0) atomicAdd(out, v);
    }
}

extern "C" void kernel_launch(void* const* d_in, const int* in_sizes, int n_in,
                              void* d_out, int out_size, void* d_ws, size_t ws_size,
                              hipStream_t stream) {
    const float* X = (const float*)d_in[0];
    const float* T = (const float*)d_in[1];
    float* out = (float*)d_out;
    float* m   = (float*)d_ws;               // [NODES][TOTPTS] = 2.0 MB

    hipMemsetAsync(out, 0, sizeof(float), stream);
    pair_min_kernel<<<2 * NGRP * NODES, BT, 0, stream>>>(X, T, m);
    combine_kernel<<<TOTPTS / 256, 256, 0, stream>>>(m, out);
}